// Round 1
// baseline (43267.520 us; speedup 1.0000x reference)
//
#include <hip/hip_runtime.h>
#include <cstdint>
#include <cstddef>

#define L2E 1.4426950408889634f

__device__ __forceinline__ float fexp2(float x){ return __builtin_amdgcn_exp2f(x); }
__device__ __forceinline__ float frcp(float x){ return __builtin_amdgcn_rcpf(x); }
// exact tanh via exp2: tanh(x) = 1 - 2/(1+exp(2x)); saturates correctly for |x| large
__device__ __forceinline__ float tanh_f(float x){
  return 1.f - 2.f*frcp(1.f + fexp2(2.f*L2E*x));
}
__device__ __forceinline__ float sigm_f(float x){
  return frcp(1.f + fexp2(-L2E*x));
}

namespace {
constexpr int NB = 32, TT = 512, DD = 768, HH = 512;
// ws offsets in floats
constexpr size_t EP_OFF  = 0;                               // epT [B][H][T]
constexpr size_t HS_OFF  = EP_OFF + (size_t)NB*HH*TT;       // hs [2][T][B][H]
constexpr size_t CST_OFF = HS_OFF + (size_t)2*TT*NB*HH;     // c state [2][B][H]
constexpr size_t DEC_OFF = CST_OFF + (size_t)2*NB*HH;       // dec [2][B][H]
constexpr size_t CTX_OFF = DEC_OFF + (size_t)2*NB*HH;       // ctx [2][B][D]
constexpr size_t GPRE_OFF= CTX_OFF + (size_t)2*NB*DD;       // gates_pre [2][B][4H]
constexpr size_t CTXP_OFF= GPRE_OFF+ (size_t)2*NB*2048;     // ctx partials [2][B][8][D]
constexpr size_t MZ_OFF  = CTXP_OFF+ (size_t)2*NB*8*DD;     // (max,Z) [2][B][8][2]
constexpr size_t WS_FLOATS = MZ_OFF + (size_t)2*NB*8*2;
}

// ---------------- enc projection: epT[b][h][t] = sum_d x[b][t][d]*Wenc[h][d] + benc[h]
__global__ void k_encproj(const float* __restrict__ x, const float* __restrict__ Wenc,
                          const float* __restrict__ benc, float* __restrict__ epT)
{
  int b = blockIdx.z, h0 = blockIdx.y*64, t0 = blockIdx.x*64;
  __shared__ float As[64][33];  // [h][k]
  __shared__ float Bs[64][33];  // [t][k]
  int tid = threadIdx.x;
  int n = tid & 63, mg = tid >> 6;       // n: t-local, mg: 4 groups of 16 h
  float acc[16];
  #pragma unroll
  for (int j = 0; j < 16; j++) acc[j] = 0.f;
  int lr = tid >> 2, lk = (tid & 3) * 8;
  for (int k0 = 0; k0 < 768; k0 += 32) {
    const float* ap = Wenc + (size_t)(h0 + lr)*768 + k0 + lk;
    #pragma unroll
    for (int i = 0; i < 8; i++) As[lr][lk + i] = ap[i];
    const float* bp = x + ((size_t)b*512 + t0 + lr)*768 + k0 + lk;
    #pragma unroll
    for (int i = 0; i < 8; i++) Bs[lr][lk + i] = bp[i];
    __syncthreads();
    #pragma unroll
    for (int kk = 0; kk < 32; kk++) {
      float bv = Bs[n][kk];
      #pragma unroll
      for (int j = 0; j < 16; j++) acc[j] += As[mg*16 + j][kk] * bv;
    }
    __syncthreads();
  }
  #pragma unroll
  for (int j = 0; j < 16; j++) {
    int h = h0 + mg*16 + j;
    epT[((size_t)b*512 + h)*512 + t0 + n] = acc[j] + benc[h];
  }
}

// ---------------- per step: dec GEMM + attention-independent gate parts
// blocks 0..31: dec[dir][b][n] = h_prev[dir][b][:] @ Wdec[n][:] + bdec[n]
// blocks 32..287: gpre[dir][b][wrow] = xt@Wih_x + h_prev@Whh + bias
__global__ void k_pre(const float* __restrict__ x, const float* __restrict__ hs,
                      const float* __restrict__ Wdec, const float* __restrict__ bdec,
                      const float* __restrict__ Wfih, const float* __restrict__ Wfhh, const float* __restrict__ bfv,
                      const float* __restrict__ Wbih, const float* __restrict__ Wbhh, const float* __restrict__ bbv,
                      float* __restrict__ dec, float* __restrict__ gpre, int s)
{
  int blk = blockIdx.x;
  int tid = threadIdx.x;
  __shared__ float A4[16][32][4];
  __shared__ float B4[16][32][4];
  if (blk < 32) {
    int dir = blk >> 4, nt = blk & 15, n0 = nt*32;
    int n = tid & 31, mg = tid >> 5;           // 8 groups x 4 m
    if (s == 0) {
      float bv = bdec[n0+n];
      #pragma unroll
      for (int j = 0; j < 4; j++) dec[((size_t)(dir*32 + mg*4+j))*512 + n0 + n] = bv;
      return;
    }
    int tr = dir ? (512 - s) : (s - 1);
    const float* A = hs + (((size_t)dir*512 + tr)*32)*512;
    float acc[4] = {0.f,0.f,0.f,0.f};
    int lr = tid >> 3, lk = (tid & 7) * 8;
    for (int k0 = 0; k0 < 512; k0 += 64) {
      const float* ap = A + (size_t)lr*512 + k0 + lk;
      float4 a0 = *(const float4*)(ap);
      float4 a1 = *(const float4*)(ap+4);
      *(float4*)&A4[lk>>2][lr][0] = a0;
      *(float4*)&A4[(lk>>2)+1][lr][0] = a1;
      const float* bp = Wdec + (size_t)(n0 + lr)*512 + k0 + lk;
      float4 b0 = *(const float4*)(bp);
      float4 b1 = *(const float4*)(bp+4);
      *(float4*)&B4[lk>>2][lr][0] = b0;
      *(float4*)&B4[(lk>>2)+1][lr][0] = b1;
      __syncthreads();
      #pragma unroll
      for (int kq = 0; kq < 16; kq++) {
        float4 bv = *(const float4*)&B4[kq][n][0];
        #pragma unroll
        for (int j = 0; j < 4; j++) {
          float4 av = *(const float4*)&A4[kq][mg*4+j][0];
          acc[j] += av.x*bv.x + av.y*bv.y + av.z*bv.z + av.w*bv.w;
        }
      }
      __syncthreads();
    }
    float bv = bdec[n0+n];
    #pragma unroll
    for (int j = 0; j < 4; j++)
      dec[((size_t)(dir*32 + mg*4+j))*512 + n0 + n] = acc[j] + bv;
  } else {
    int pb = blk - 32;
    int dir = pb >> 7, jt = pb & 127, j0 = jt*4;
    const float* Wih = dir ? Wbih : Wfih;
    const float* Whh = dir ? Wbhh : Wfhh;
    const float* bias = dir ? bbv : bfv;
    int t_in = dir ? (511 - s) : s;
    int tr = dir ? (512 - s) : (s - 1);
    int n = tid & 15, mg = tid >> 4;           // 16 groups x 2 m
    float acc[2] = {0.f,0.f};
    int kmax = (s == 0) ? 768 : 1280;
    int alr = tid >> 3, alk = (tid & 7) * 8;
    int blr = tid >> 4, bk2 = (tid & 15) * 4;
    int wrow_l = ((blr >> 2) * 512) + j0 + (blr & 3);
    for (int k0 = 0; k0 < kmax; k0 += 64) {
      const float* ap;
      if (k0 < 768) ap = x + ((size_t)alr*512 + t_in)*768 + k0 + alk;
      else          ap = hs + (((size_t)dir*512 + tr)*32 + alr)*512 + (k0 - 768) + alk;
      float4 a0 = *(const float4*)(ap);
      float4 a1 = *(const float4*)(ap+4);
      *(float4*)&A4[alk>>2][alr][0] = a0;
      *(float4*)&A4[(alk>>2)+1][alr][0] = a1;
      const float* bp;
      if (k0 < 768) bp = Wih + (size_t)wrow_l*1536 + 768 + k0 + bk2;
      else          bp = Whh + (size_t)wrow_l*512 + (k0 - 768) + bk2;
      *(float4*)&B4[bk2>>2][blr][0] = *(const float4*)(bp);
      __syncthreads();
      #pragma unroll
      for (int kq = 0; kq < 16; kq++) {
        float4 bv = *(const float4*)&B4[kq][n][0];
        #pragma unroll
        for (int j = 0; j < 2; j++) {
          float4 av = *(const float4*)&A4[kq][mg*2+j][0];
          acc[j] += av.x*bv.x + av.y*bv.y + av.z*bv.z + av.w*bv.w;
        }
      }
      __syncthreads();
    }
    int wr = ((n >> 2)*512) + j0 + (n & 3);
    float bv = bias[wr];
    #pragma unroll
    for (int j = 0; j < 2; j++)
      gpre[((size_t)dir*32 + mg*2+j)*2048 + wr] = acc[j] + bv;
  }
}

// ---------------- attention part 1: scores+chunk softmax+partial ctx, WG per (b, t-chunk)
__global__ void k_attn1(const float* __restrict__ ep, const float* __restrict__ dec,
                        const float* __restrict__ v, const float* __restrict__ x,
                        float* __restrict__ ctxp, float* __restrict__ mz)
{
  int tc = blockIdx.x, b = blockIdx.y, t0 = tc*64;
  int tid = threadIdx.x;
  __shared__ float d0s[512], d1s[512], vs[512];
  __shared__ float p0s[64], p1s[64];
  d0s[tid] = dec[(size_t)b*512 + tid];
  d1s[tid] = dec[((size_t)32 + b)*512 + tid];
  vs[tid]  = v[tid];
  __syncthreads();
  int tl = tid & 63, hg = tid >> 6;   // 8 h-groups of 64
  float sc0 = 0.f, sc1 = 0.f;
  const float* epp = ep + ((size_t)b*512)*512 + t0 + tl;
  #pragma unroll 4
  for (int h = hg*64; h < hg*64 + 64; h++) {
    float e = epp[(size_t)h*512];
    float vv = vs[h];
    sc0 += tanh_f(e + d0s[h]) * vv;
    sc1 += tanh_f(e + d1s[h]) * vv;
  }
  __syncthreads();
  d0s[hg*64 + tl] = sc0;
  d1s[hg*64 + tl] = sc1;
  __syncthreads();
  if (tid < 64) {
    float s0 = 0.f, s1 = 0.f;
    #pragma unroll
    for (int g = 0; g < 8; g++) { s0 += d0s[g*64 + tid]; s1 += d1s[g*64 + tid]; }
    float m0 = s0, m1 = s1;
    #pragma unroll
    for (int off = 32; off; off >>= 1) {
      m0 = fmaxf(m0, __shfl_xor(m0, off));
      m1 = fmaxf(m1, __shfl_xor(m1, off));
    }
    float p0 = fexp2((s0 - m0)*L2E);
    float p1 = fexp2((s1 - m1)*L2E);
    float z0 = p0, z1 = p1;
    #pragma unroll
    for (int off = 32; off; off >>= 1) { z0 += __shfl_xor(z0, off); z1 += __shfl_xor(z1, off); }
    p0s[tid] = p0; p1s[tid] = p1;
    if (tid == 0) {
      float* q0 = mz + ((size_t)(b)*8 + tc)*2;        q0[0] = m0; q0[1] = z0;
      float* q1 = mz + ((size_t)(32 + b)*8 + tc)*2;   q1[0] = m1; q1[1] = z1;
    }
  }
  __syncthreads();
  const float* xb = x + ((size_t)b*512 + t0)*768;
  for (int dd = tid; dd < 768; dd += 512) {
    float a0 = 0.f, a1 = 0.f;
    #pragma unroll 8
    for (int t = 0; t < 64; t++) {
      float xv = xb[(size_t)t*768 + dd];
      a0 += p0s[t]*xv;
      a1 += p1s[t]*xv;
    }
    ctxp[((size_t)(b)*8 + tc)*768 + dd] = a0;
    ctxp[((size_t)(32 + b)*8 + tc)*768 + dd] = a1;
  }
}

// ---------------- attention part 2: merge chunk partials -> ctx
__global__ void k_attn2(const float* __restrict__ ctxp, const float* __restrict__ mz,
                        float* __restrict__ ctx)
{
  int dir = blockIdx.x, b = blockIdx.y;
  int tid = threadIdx.x;
  __shared__ float scs[8];
  __shared__ float zinv_s;
  if (tid == 0) {
    const float* q = mz + ((size_t)dir*32 + b)*8*2;
    float gm = q[0];
    #pragma unroll
    for (int c2 = 1; c2 < 8; c2++) gm = fmaxf(gm, q[c2*2]);
    float Z = 0.f;
    #pragma unroll
    for (int c2 = 0; c2 < 8; c2++) {
      float scl = fexp2((q[c2*2] - gm)*L2E);
      scs[c2] = scl;
      Z += q[c2*2+1]*scl;
    }
    zinv_s = 1.f / Z;
  }
  __syncthreads();
  float zi = zinv_s;
  const float* cp = ctxp + ((size_t)dir*32 + b)*8*768;
  for (int dd = tid; dd < 768; dd += 256) {
    float a = 0.f;
    #pragma unroll
    for (int c2 = 0; c2 < 8; c2++) a += cp[(size_t)c2*768 + dd]*scs[c2];
    ctx[((size_t)dir*32 + b)*768 + dd] = a*zi;
  }
}

// ---------------- gates final: ctx-part GEMM + LSTM update
__global__ void k_fin(const float* __restrict__ ctx, const float* __restrict__ Wfih, const float* __restrict__ Wbih,
                      const float* __restrict__ gpre, float* __restrict__ hs, float* __restrict__ cst, int s)
{
  int blk = blockIdx.x;
  int dir = blk >> 7, jt = blk & 127, j0 = jt*4;
  const float* Wih = dir ? Wbih : Wfih;
  int tid = threadIdx.x;
  __shared__ float A4[16][32][4];
  __shared__ float B4[16][16][4];
  __shared__ float gsm[16][33];
  int n = tid & 15, mg = tid >> 4;
  float acc[2] = {0.f,0.f};
  int alr = tid >> 3, alk = (tid & 7)*8;
  int blr = tid >> 4, bk2 = (tid & 15)*4;
  int wrow_l = ((blr >> 2)*512) + j0 + (blr & 3);
  const float* ab = ctx + (size_t)dir*32*768;
  for (int k0 = 0; k0 < 768; k0 += 64) {
    const float* ap = ab + (size_t)alr*768 + k0 + alk;
    *(float4*)&A4[alk>>2][alr][0] = *(const float4*)(ap);
    *(float4*)&A4[(alk>>2)+1][alr][0] = *(const float4*)(ap+4);
    const float* bp = Wih + (size_t)wrow_l*1536 + k0 + bk2;
    *(float4*)&B4[bk2>>2][blr][0] = *(const float4*)(bp);
    __syncthreads();
    #pragma unroll
    for (int kq = 0; kq < 16; kq++) {
      float4 bv = *(const float4*)&B4[kq][n][0];
      #pragma unroll
      for (int j = 0; j < 2; j++) {
        float4 av = *(const float4*)&A4[kq][mg*2+j][0];
        acc[j] += av.x*bv.x + av.y*bv.y + av.z*bv.z + av.w*bv.w;
      }
    }
    __syncthreads();
  }
  int wr = ((n >> 2)*512) + j0 + (n & 3);
  #pragma unroll
  for (int j = 0; j < 2; j++)
    gsm[n][mg*2+j] = acc[j] + gpre[((size_t)dir*32 + mg*2+j)*2048 + wr];
  __syncthreads();
  if (tid < 128) {
    int b = tid >> 2, jj = tid & 3;
    float gi = gsm[jj][b];
    float gf = gsm[4+jj][b];
    float gg = gsm[8+jj][b];
    float go = gsm[12+jj][b];
    size_t ci = ((size_t)dir*32 + b)*512 + j0 + jj;
    float c_old = cst[ci];
    float cn = sigm_f(gf)*c_old + sigm_f(gi)*tanh_f(gg);
    float h = sigm_f(go)*tanh_f(cn);
    cst[ci] = cn;
    int tw = dir ? (511 - s) : s;
    hs[(((size_t)dir*512 + tw)*32 + b)*512 + j0 + jj] = h;
  }
}

// ---------------- head: out[b][t][c] = [hf|hb] @ Whead^T + bhead
__global__ void k_head(const float* __restrict__ hs, const float* __restrict__ Wh,
                       const float* __restrict__ bh, float* __restrict__ out)
{
  int wid = threadIdx.x >> 6, lane = threadIdx.x & 63;
  int r = blockIdx.x*4 + wid;
  int b = r >> 9, t = r & 511;
  float acc[7];
  #pragma unroll
  for (int c2 = 0; c2 < 7; c2++) acc[c2] = 0.f;
  const float* hf = hs + (((size_t)t)*32 + b)*512;
  const float* hb = hs + (((size_t)512 + t)*32 + b)*512;
  for (int k0 = 0; k0 < 512; k0 += 64) {
    int k = k0 + lane;
    float a = hf[k], bvv = hb[k];
    #pragma unroll
    for (int c2 = 0; c2 < 7; c2++)
      acc[c2] += a*Wh[c2*1024 + k] + bvv*Wh[c2*1024 + 512 + k];
  }
  #pragma unroll
  for (int c2 = 0; c2 < 7; c2++) {
    float sres = acc[c2];
    #pragma unroll
    for (int off = 32; off; off >>= 1) sres += __shfl_xor(sres, off);
    if (lane == c2) out[((size_t)b*512 + t)*7 + c2] = sres + bh[c2];
  }
}

extern "C" void kernel_launch(void* const* d_in, const int* in_sizes, int n_in,
                              void* d_out, int out_size, void* d_ws, size_t ws_size,
                              hipStream_t stream) {
  (void)in_sizes; (void)n_in; (void)out_size;
  const float* x    = (const float*)d_in[0];
  const float* Wfih = (const float*)d_in[1];
  const float* Wfhh = (const float*)d_in[2];
  const float* bfv  = (const float*)d_in[3];
  const float* Wbih = (const float*)d_in[4];
  const float* Wbhh = (const float*)d_in[5];
  const float* bbv  = (const float*)d_in[6];
  const float* Wenc = (const float*)d_in[7];
  const float* benc = (const float*)d_in[8];
  const float* Wdec = (const float*)d_in[9];
  const float* bdec = (const float*)d_in[10];
  const float* v    = (const float*)d_in[11];
  const float* Whead= (const float*)d_in[12];
  const float* bhead= (const float*)d_in[13];
  float* out = (float*)d_out;
  float* ws  = (float*)d_ws;

  if (ws_size < WS_FLOATS * sizeof(float)) return;  // insufficient scratch

  float* ep   = ws + EP_OFF;
  float* hs   = ws + HS_OFF;
  float* cst  = ws + CST_OFF;
  float* dec  = ws + DEC_OFF;
  float* ctx  = ws + CTX_OFF;
  float* gpre = ws + GPRE_OFF;
  float* ctxp = ws + CTXP_OFF;
  float* mz   = ws + MZ_OFF;

  hipMemsetAsync(cst, 0, (size_t)2*NB*HH*sizeof(float), stream);
  hipLaunchKernelGGL(k_encproj, dim3(8,8,32), dim3(256), 0, stream, x, Wenc, benc, ep);
  for (int s = 0; s < TT; s++) {
    hipLaunchKernelGGL(k_pre, dim3(288), dim3(256), 0, stream,
                       x, hs, Wdec, bdec, Wfih, Wfhh, bfv, Wbih, Wbhh, bbv, dec, gpre, s);
    hipLaunchKernelGGL(k_attn1, dim3(8,32), dim3(512), 0, stream, ep, dec, v, x, ctxp, mz);
    hipLaunchKernelGGL(k_attn2, dim3(2,32), dim3(256), 0, stream, ctxp, mz, ctx);
    hipLaunchKernelGGL(k_fin, dim3(256), dim3(256), 0, stream, ctx, Wfih, Wbih, gpre, hs, cst, s);
  }
  hipLaunchKernelGGL(k_head, dim3(4096), dim3(256), 0, stream, hs, Whead, bhead, out);
}

// Round 2
// 19232.767 us; speedup vs baseline: 2.2497x; 2.2497x over previous
//
#include <hip/hip_runtime.h>
#include <cstdint>
#include <cstddef>

#define L2E 1.4426950408889634f

typedef __attribute__((ext_vector_type(8))) short short8v;
typedef __attribute__((ext_vector_type(4))) float f32x4;

__device__ __forceinline__ float fexp2(float x){ return __builtin_amdgcn_exp2f(x); }
__device__ __forceinline__ float frcp(float x){ return __builtin_amdgcn_rcpf(x); }
__device__ __forceinline__ float tanh_f(float x){
  return 1.f - 2.f*frcp(1.f + fexp2(2.f*L2E*x));
}
__device__ __forceinline__ float sigm_f(float x){
  return frcp(1.f + fexp2(-L2E*x));
}
__device__ __forceinline__ float bf2f(ushort u){ return __uint_as_float(((uint32_t)u)<<16); }
__device__ __forceinline__ ushort f2bf(float f){
  uint32_t x = __float_as_uint(f);
  uint32_t r = (x + 0x7FFFu + ((x>>16)&1u)) >> 16;
  return (ushort)r;
}

namespace {
constexpr int NB = 32, TT = 512, DD = 768, HH = 512;
// byte offsets into ws
constexpr size_t EPB  = 0;                               // ep bf16 [B][H][T]
constexpr size_t XBB  = EPB  + (size_t)NB*HH*TT*2;       // x bf16 [B][T][D]
constexpr size_t HSB  = XBB  + (size_t)NB*TT*DD*2;       // hs bf16 [2][T][B][H]
constexpr size_t WPKB = HSB  + (size_t)2*TT*NB*HH*2;     // Wpack bf16 [2][128][64][64][8]
constexpr size_t UCTXB= WPKB + (size_t)2*128*64*64*8*2;  // uctx f32 [2][B][D]
constexpr size_t ZBB  = UCTXB+ (size_t)2*NB*DD*4;        // Z f32 [2][B]
constexpr size_t DECB = ZBB  + (size_t)2*NB*4;           // dec f32 [2][B][H]
constexpr size_t CSTB = DECB + (size_t)2*NB*HH*4;        // c f32 [2][B][H]
constexpr size_t WS_BYTES = CSTB + (size_t)2*NB*HH*4;
}

// ---------------- x -> bf16
__global__ void k_xcast(const float* __restrict__ x, ushort* __restrict__ xb)
{
  size_t i = ((size_t)blockIdx.x*256 + threadIdx.x)*8;
  float4 v0 = *(const float4*)(x + i);
  float4 v1 = *(const float4*)(x + i + 4);
  short8v o;
  o[0]=(short)f2bf(v0.x); o[1]=(short)f2bf(v0.y); o[2]=(short)f2bf(v0.z); o[3]=(short)f2bf(v0.w);
  o[4]=(short)f2bf(v1.x); o[5]=(short)f2bf(v1.y); o[6]=(short)f2bf(v1.z); o[7]=(short)f2bf(v1.w);
  *(short8v*)(xb + i) = o;
}

// ---------------- enc projection: ep[b][h][t] = x[b][t][:]·Wenc[h][:] + benc[h] (fp32 math, bf16 out)
__global__ void k_encproj(const float* __restrict__ x, const float* __restrict__ Wenc,
                          const float* __restrict__ benc, ushort* __restrict__ epT)
{
  int b = blockIdx.z, h0 = blockIdx.y*64, t0 = blockIdx.x*64;
  __shared__ float As[64][33];
  __shared__ float Bs[64][33];
  int tid = threadIdx.x;
  int n = tid & 63, mg = tid >> 6;
  float acc[16];
  #pragma unroll
  for (int j = 0; j < 16; j++) acc[j] = 0.f;
  int lr = tid >> 2, lk = (tid & 3) * 8;
  for (int k0 = 0; k0 < 768; k0 += 32) {
    const float* ap = Wenc + (size_t)(h0 + lr)*768 + k0 + lk;
    #pragma unroll
    for (int i = 0; i < 8; i++) As[lr][lk + i] = ap[i];
    const float* bp = x + ((size_t)b*512 + t0 + lr)*768 + k0 + lk;
    #pragma unroll
    for (int i = 0; i < 8; i++) Bs[lr][lk + i] = bp[i];
    __syncthreads();
    #pragma unroll
    for (int kk = 0; kk < 32; kk++) {
      float bv = Bs[n][kk];
      #pragma unroll
      for (int j = 0; j < 16; j++) acc[j] += As[mg*16 + j][kk] * bv;
    }
    __syncthreads();
  }
  #pragma unroll
  for (int j = 0; j < 16; j++) {
    int h = h0 + mg*16 + j;
    epT[((size_t)b*512 + h)*512 + t0 + n] = f2bf(acc[j] + benc[h]);
  }
}

// ---------------- pre-pack gate weights into MFMA fragment order
// Wpack[dir][jblk][kstep][lane][0..7]; col c=lane&15 -> row=(c>>2)*512 + jblk*4 + (c&3)
// k = kstep*32 + (lane>>4)*8 + i ; k<512 -> Whh[row][k] ; else Wih[row][k-512]
__global__ void k_wpack(const float* __restrict__ Wfih, const float* __restrict__ Wfhh,
                        const float* __restrict__ Wbih, const float* __restrict__ Wbhh,
                        ushort* __restrict__ wpk)
{
  size_t f = (size_t)blockIdx.x*256 + threadIdx.x;   // 1,048,576 total
  int lane = (int)(f & 63), kstep = (int)((f>>6)&63), jblk = (int)((f>>12)&127), dir = (int)(f>>19);
  const float* Whh = dir ? Wbhh : Wfhh;
  const float* Wih = dir ? Wbih : Wfih;
  int c = lane & 15, gate = c >> 2, jj = c & 3;
  int row = gate*512 + jblk*4 + jj;
  int kbase = kstep*32 + (lane>>4)*8;
  short8v o;
  #pragma unroll
  for (int i = 0; i < 8; i++) {
    int k = kbase + i;
    float w = (k < 512) ? Whh[(size_t)row*512 + k] : Wih[(size_t)row*1536 + (k - 512)];
    o[i] = (short)f2bf(w);
  }
  *(short8v*)(wpk + f*8) = o;
}

// ---------------- per step: dec = h_prev·Wdec^T + bdec ; also zero uctx/Z for this step
__global__ __launch_bounds__(256) void k_d(const ushort* __restrict__ hsb, const float* __restrict__ Wdec,
                                           const float* __restrict__ bdec, float* __restrict__ dec,
                                           float* __restrict__ uctx, float* __restrict__ Zb, int s)
{
  int bid = blockIdx.x;
  int tid = threadIdx.x;
  // zero uctx (49152) + Z (64)
  int idx = bid*256 + tid;
  if (idx < 2*32*768) uctx[idx] = 0.f;
  else if (idx < 2*32*768 + 64) Zb[idx - 2*32*768] = 0.f;

  int dir = bid >> 7, jc = bid & 127, j0 = jc*4;
  __shared__ float hls[32][513];
  __shared__ float wls[4][520];
  __shared__ float red2[256];
  int kh = tid >> 7, jloc = (tid >> 5) & 3, b = tid & 31;
  if (s > 0) {
    int t_prev = dir ? (512 - s) : (s - 1);
    for (int i = tid; i < 2048; i += 256) {         // 32 rows x 64 chunks of 8
      int row = i >> 6, col = (i & 63) * 8;
      const ushort* src = hsb + (((size_t)dir*512 + t_prev)*32 + row)*512 + col;
      short8v v8 = *(const short8v*)src;
      #pragma unroll
      for (int j = 0; j < 8; j++) hls[row][col + j] = bf2f((ushort)v8[j]);
    }
    for (int i = tid; i < 2048; i += 256) {
      int row = i >> 9, col = i & 511;
      wls[row][col] = Wdec[(size_t)(j0 + row)*512 + col];
    }
  }
  __syncthreads();
  float acc = 0.f;
  if (s > 0) {
    int k0 = kh*256;
    #pragma unroll 8
    for (int k = k0; k < k0 + 256; k++) acc += hls[b][k]*wls[jloc][k];
  }
  red2[tid] = acc;
  __syncthreads();
  if (tid < 128) {
    int b2 = tid & 31, jl2 = (tid >> 5) & 3;
    float dv = red2[tid] + red2[tid + 128] + bdec[j0 + jl2];
    dec[((size_t)dir*32 + b2)*512 + j0 + jl2] = dv;
  }
}

// ---------------- per step: scores + shifted exp + unnormalized ctx via atomics
__global__ __launch_bounds__(512) void k_sc(const ushort* __restrict__ ep, const ushort* __restrict__ xb,
                                            const float* __restrict__ dec, const float* __restrict__ vg,
                                            float* __restrict__ uctx, float* __restrict__ Zb)
{
  int b = blockIdx.x >> 3, tc = blockIdx.x & 7, t0 = tc*64;
  int tid = threadIdx.x;
  __shared__ float d0[512], d1[512], vs[512];
  __shared__ float scr[2][8][64];
  __shared__ float ev[2][64];
  d0[tid] = dec[(size_t)b*512 + tid];
  d1[tid] = dec[((size_t)32 + b)*512 + tid];
  vs[tid] = vg[tid];
  __syncthreads();
  int tl = tid & 63, hg = tid >> 6;
  const ushort* epp = ep + ((size_t)b*512 + hg*64)*512 + t0 + tl;
  float s0 = 0.f, s1 = 0.f;
  #pragma unroll 8
  for (int hh = 0; hh < 64; hh++) {
    int h = hg*64 + hh;
    float e = bf2f(__builtin_nontemporal_load(epp)); epp += 512;
    s0 += tanh_f(e + d0[h]) * vs[h];
    s1 += tanh_f(e + d1[h]) * vs[h];
  }
  scr[0][hg][tl] = s0; scr[1][hg][tl] = s1;
  __syncthreads();
  if (tid < 128) {
    int dq = tid >> 6, tq = tid & 63;
    float sv = 0.f;
    #pragma unroll
    for (int g = 0; g < 8; g++) sv += scr[dq][g][tq];
    sv = fminf(sv, 100.f);
    float e = fexp2((sv - 32.f)*L2E);
    ev[dq][tq] = e;
    float z = e;
    #pragma unroll
    for (int off = 32; off; off >>= 1) z += __shfl_xor(z, off);
    if (tq == 0) atomicAdd(Zb + dq*32 + b, z);
  }
  __syncthreads();
  for (int dd = tid; dd < 768; dd += 512) {
    const ushort* xp = xb + ((size_t)b*512 + t0)*768 + dd;
    float a0 = 0.f, a1 = 0.f;
    #pragma unroll 8
    for (int t = 0; t < 64; t++) {
      float xv = bf2f(__builtin_nontemporal_load(xp + (size_t)t*768));
      a0 += ev[0][t]*xv;
      a1 += ev[1][t]*xv;
    }
    atomicAdd(uctx + (size_t)b*768 + dd, a0);
    atomicAdd(uctx + ((size_t)32 + b)*768 + dd, a1);
  }
}

// ---------------- per step: gates MFMA GEMM (K=2048 = h|ctx|x) + fused LSTM pointwise
__global__ __launch_bounds__(512) void k_g(ushort* __restrict__ hsb, const ushort* __restrict__ xb,
                                           const ushort* __restrict__ wpk, const float* __restrict__ uctx,
                                           const float* __restrict__ Zb, const float* __restrict__ bfv,
                                           const float* __restrict__ bbv, float* __restrict__ cst, int s)
{
  int bid = blockIdx.x;
  int dir = bid >> 7, jblk = bid & 127;
  int tid = threadIdx.x, wid = tid >> 6, lane = tid & 63;
  int t_in = dir ? (511 - s) : s;
  int l15 = lane & 15, lk8 = (lane >> 4) * 8;
  int b0 = l15, b1 = 16 + l15;
  __shared__ float red[8][32][16];
  __shared__ float gfin[32][17];
  f32x4 acc0 = {0,0,0,0}, acc1 = {0,0,0,0};
  const ushort* wpb = wpk + (((size_t)dir*128 + jblk)*64)*512;

  if (wid < 2) {                       // ksteps 0..15 : h_prev part
    if (s > 0) {
      int t_prev = dir ? (512 - s) : (s - 1);
      const ushort* h0 = hsb + (((size_t)dir*512 + t_prev)*32 + b0)*512;
      const ushort* h1 = hsb + (((size_t)dir*512 + t_prev)*32 + b1)*512;
      #pragma unroll
      for (int kk = 0; kk < 8; kk++) {
        int kstep = wid*8 + kk;
        int ko = kstep*32 + lk8;
        short8v a0v = *(const short8v*)(h0 + ko);
        short8v a1v = *(const short8v*)(h1 + ko);
        short8v bv  = *(const short8v*)(wpb + (size_t)kstep*512 + lane*8);
        acc0 = __builtin_amdgcn_mfma_f32_16x16x32_bf16(a0v, bv, acc0, 0, 0, 0);
        acc1 = __builtin_amdgcn_mfma_f32_16x16x32_bf16(a1v, bv, acc1, 0, 0, 0);
      }
    }
  } else if (wid < 5) {                // ksteps 16..39 : ctx part (uctx * 1/Z)
    float zi0 = 1.0f / Zb[dir*32 + b0];
    float zi1 = 1.0f / Zb[dir*32 + b1];
    const float* u0 = uctx + ((size_t)dir*32 + b0)*768;
    const float* u1 = uctx + ((size_t)dir*32 + b1)*768;
    #pragma unroll
    for (int kk = 0; kk < 8; kk++) {
      int kstep = wid*8 + kk;
      int ko = kstep*32 - 512 + lk8;
      float4 xa = *(const float4*)(u0 + ko);
      float4 xb4 = *(const float4*)(u0 + ko + 4);
      float4 ya = *(const float4*)(u1 + ko);
      float4 yb = *(const float4*)(u1 + ko + 4);
      short8v a0v, a1v;
      a0v[0]=(short)f2bf(xa.x*zi0);  a0v[1]=(short)f2bf(xa.y*zi0);
      a0v[2]=(short)f2bf(xa.z*zi0);  a0v[3]=(short)f2bf(xa.w*zi0);
      a0v[4]=(short)f2bf(xb4.x*zi0); a0v[5]=(short)f2bf(xb4.y*zi0);
      a0v[6]=(short)f2bf(xb4.z*zi0); a0v[7]=(short)f2bf(xb4.w*zi0);
      a1v[0]=(short)f2bf(ya.x*zi1);  a1v[1]=(short)f2bf(ya.y*zi1);
      a1v[2]=(short)f2bf(ya.z*zi1);  a1v[3]=(short)f2bf(ya.w*zi1);
      a1v[4]=(short)f2bf(yb.x*zi1);  a1v[5]=(short)f2bf(yb.y*zi1);
      a1v[6]=(short)f2bf(yb.z*zi1);  a1v[7]=(short)f2bf(yb.w*zi1);
      short8v bv = *(const short8v*)(wpb + (size_t)kstep*512 + lane*8);
      acc0 = __builtin_amdgcn_mfma_f32_16x16x32_bf16(a0v, bv, acc0, 0, 0, 0);
      acc1 = __builtin_amdgcn_mfma_f32_16x16x32_bf16(a1v, bv, acc1, 0, 0, 0);
    }
  } else {                             // ksteps 40..63 : x part
    const ushort* x0 = xb + ((size_t)b0*512 + t_in)*768;
    const ushort* x1 = xb + ((size_t)b1*512 + t_in)*768;
    #pragma unroll
    for (int kk = 0; kk < 8; kk++) {
      int kstep = wid*8 + kk;
      int ko = kstep*32 - 1280 + lk8;
      short8v a0v = *(const short8v*)(x0 + ko);
      short8v a1v = *(const short8v*)(x1 + ko);
      short8v bv  = *(const short8v*)(wpb + (size_t)kstep*512 + lane*8);
      acc0 = __builtin_amdgcn_mfma_f32_16x16x32_bf16(a0v, bv, acc0, 0, 0, 0);
      acc1 = __builtin_amdgcn_mfma_f32_16x16x32_bf16(a1v, bv, acc1, 0, 0, 0);
    }
  }

  int rr = (lane >> 4) * 4;
  #pragma unroll
  for (int r = 0; r < 4; r++) red[wid][rr + r][l15] = acc0[r];
  #pragma unroll
  for (int r = 0; r < 4; r++) red[wid][16 + rr + r][l15] = acc1[r];
  __syncthreads();
  {
    int b = tid >> 4, c = tid & 15;
    float g = 0.f;
    #pragma unroll
    for (int w = 0; w < 8; w++) g += red[w][b][c];
    gfin[b][c] = g;
  }
  __syncthreads();
  if (tid < 128) {
    int b = tid >> 2, jj = tid & 3;
    int j = jblk*4 + jj;
    const float* bias = dir ? bbv : bfv;
    float gi = gfin[b][jj]      + bias[j];
    float gf = gfin[b][4 + jj]  + bias[512 + j];
    float gg = gfin[b][8 + jj]  + bias[1024 + j];
    float go = gfin[b][12 + jj] + bias[1536 + j];
    size_t ci = ((size_t)dir*32 + b)*512 + j;
    float co = cst[ci];
    float cn = sigm_f(gf)*co + sigm_f(gi)*tanh_f(gg);
    float h  = sigm_f(go)*tanh_f(cn);
    cst[ci] = cn;
    int tw = dir ? (511 - s) : s;
    hsb[(((size_t)dir*512 + tw)*32 + b)*512 + j] = f2bf(h);
  }
}

// ---------------- head: out[b][t][c] = [hf|hb]·Whead^T + bhead
__global__ void k_head(const ushort* __restrict__ hsb, const float* __restrict__ Wh,
                       const float* __restrict__ bh, float* __restrict__ out)
{
  int wid = threadIdx.x >> 6, lane = threadIdx.x & 63;
  int r = blockIdx.x*4 + wid;
  int b = r >> 9, t = r & 511;
  float acc[7];
  #pragma unroll
  for (int c = 0; c < 7; c++) acc[c] = 0.f;
  const ushort* hf = hsb + (((size_t)t)*32 + b)*512;
  const ushort* hb = hsb + (((size_t)512 + t)*32 + b)*512;
  for (int k0 = 0; k0 < 512; k0 += 64) {
    int k = k0 + lane;
    float a = bf2f(hf[k]), bvv = bf2f(hb[k]);
    #pragma unroll
    for (int c = 0; c < 7; c++)
      acc[c] += a*Wh[c*1024 + k] + bvv*Wh[c*1024 + 512 + k];
  }
  #pragma unroll
  for (int c = 0; c < 7; c++) {
    float sres = acc[c];
    #pragma unroll
    for (int off = 32; off; off >>= 1) sres += __shfl_xor(sres, off);
    if (lane == c) out[((size_t)b*512 + t)*7 + c] = sres + bh[c];
  }
}

extern "C" void kernel_launch(void* const* d_in, const int* in_sizes, int n_in,
                              void* d_out, int out_size, void* d_ws, size_t ws_size,
                              hipStream_t stream) {
  (void)in_sizes; (void)n_in; (void)out_size;
  const float* x    = (const float*)d_in[0];
  const float* Wfih = (const float*)d_in[1];
  const float* Wfhh = (const float*)d_in[2];
  const float* bfv  = (const float*)d_in[3];
  const float* Wbih = (const float*)d_in[4];
  const float* Wbhh = (const float*)d_in[5];
  const float* bbv  = (const float*)d_in[6];
  const float* Wenc = (const float*)d_in[7];
  const float* benc = (const float*)d_in[8];
  const float* Wdec = (const float*)d_in[9];
  const float* bdec = (const float*)d_in[10];
  const float* v    = (const float*)d_in[11];
  const float* Whead= (const float*)d_in[12];
  const float* bhead= (const float*)d_in[13];
  float* out = (float*)d_out;
  char* ws = (char*)d_ws;

  if (ws_size < WS_BYTES) return;

  ushort* ep   = (ushort*)(ws + EPB);
  ushort* xb   = (ushort*)(ws + XBB);
  ushort* hsb  = (ushort*)(ws + HSB);
  ushort* wpk  = (ushort*)(ws + WPKB);
  float*  uctx = (float*)(ws + UCTXB);
  float*  Zb   = (float*)(ws + ZBB);
  float*  dec  = (float*)(ws + DECB);
  float*  cst  = (float*)(ws + CSTB);

  hipMemsetAsync(ws + UCTXB, 0, (size_t)(ZBB + 2*NB*4 - UCTXB), stream);
  hipMemsetAsync(ws + CSTB, 0, (size_t)2*NB*HH*4, stream);

  hipLaunchKernelGGL(k_xcast, dim3(6144), dim3(256), 0, stream, x, xb);
  hipLaunchKernelGGL(k_encproj, dim3(8,8,32), dim3(256), 0, stream, x, Wenc, benc, ep);
  hipLaunchKernelGGL(k_wpack, dim3(4096), dim3(256), 0, stream, Wfih, Wfhh, Wbih, Wbhh, wpk);

  for (int s = 0; s < TT; s++) {
    hipLaunchKernelGGL(k_d, dim3(256), dim3(256), 0, stream, hsb, Wdec, bdec, dec, uctx, Zb, s);
    hipLaunchKernelGGL(k_sc, dim3(256), dim3(512), 0, stream, ep, xb, dec, v, uctx, Zb);
    hipLaunchKernelGGL(k_g, dim3(256), dim3(512), 0, stream, hsb, xb, wpk, uctx, Zb, bfv, bbv, cst, s);
  }
  hipLaunchKernelGGL(k_head, dim3(4096), dim3(256), 0, stream, hsb, Whead, bhead, out);
}